// Round 11
// baseline (143.995 us; speedup 1.0000x reference)
//
#include <hip/hip_runtime.h>
#include <math.h>

// Weighted Hausdorff Distance — B=8, H=W=256 (N=65536 pixels), G=128.
// SINGLE fused kernel. Main compute: 8-lane groups share a pixel-pair; each
// lane owns a 16-g chunk as 8 packed g-pairs (v2f -> v_pk_* f32 on gfx950).
// GT coords in SoA LDS (ysx/ysy), chunk stride 18: conflict-free ds_read_b64.
// Partials: part[row][132], row = b*128 + blk. cols 0..127 per-g sums of
// (wd+1e-6)^-9; col 128 sum p*min_d; col 129 sum p.
// Completion protocol (d_ws is 0xAA-poisoned before EVERY launch, so counters
// start at 0xAAAAAAAA): per-b counter at RES_OFF+32+b — the block seeing
// old == 0xAAAAAAAA+127 finalizes batch b (all 128 writers fenced before
// incrementing); global counter at RES_OFF+40 — old == 0xAAAAAAAA+7 combines.

#define HH 256
#define WW 256
#define BB 8
#define GG 128
#define NPIX (HH * WW)
#define BPB 128                       // blocks per batch item
#define ROWW 132                      // padded row width
#define RES_OFF (1024 * ROWW)
#define MAXD 362.03867196751236f      // sqrt(256^2 + 256^2)
#define POISON 0xAAAAAAAAu
#define TGT_B (POISON + 127u)
#define TGT_G (POISON + 7u)

typedef float v2f __attribute__((ext_vector_type(2)));

__device__ __forceinline__ float wave_sum(float v) {
    v += __shfl_xor(v, 1);  v += __shfl_xor(v, 2);  v += __shfl_xor(v, 4);
    v += __shfl_xor(v, 8);  v += __shfl_xor(v, 16); v += __shfl_xor(v, 32);
    return v;
}

__global__ __launch_bounds__(256, 4) void whd_fused(const float* __restrict__ prob,
                                                    const float* __restrict__ gt,
                                                    const float* __restrict__ osz,
                                                    float* __restrict__ part,
                                                    float* __restrict__ out) {
    const int bid  = blockIdx.x;
    const int b    = bid >> 7;            // / BPB
    const int blk  = bid & (BPB - 1);
    const int tid  = threadIdx.x;
    const int lane = tid & 63;
    const int wv   = tid >> 6;
    const int chunk = tid & 7;            // which 16-g chunk this lane owns
    const int pt    = tid >> 3;           // pixel-slot id, 0..31

    __shared__ float ysx[144];            // SoA, chunk c at offset c*18
    __shared__ float ysy[144];
    __shared__ float redS[4][137];
    __shared__ float2 redT[4];
    __shared__ unsigned int doFin;
    __shared__ float sh[128];
    __shared__ float rA[4], rT[4], rP[4];

    const float nh = osz[b * 2]     * (1.0f / (float)HH);
    const float nw = osz[b * 2 + 1] * (1.0f / (float)WW);

    if (tid < GG) {
        float gr = gt[(b * GG + tid) * 2];
        float gc = gt[(b * GG + tid) * 2 + 1];
        const int idx = (tid >> 4) * 18 + (tid & 15);
        ysx[idx] = gr * nh;
        ysy[idx] = gc * nw;
    }
    __syncthreads();

    const float* pb = prob + b * NPIX;

    v2f acc2[8];
#pragma unroll
    for (int j = 0; j < 8; j++) acc2[j] = (v2f)(0.0f);
    float t1acc = 0.0f, pacc = 0.0f;

    const int ysbase = chunk * 18;
    const int pix0   = blk * 512 + pt;

#pragma unroll 1
    for (int i = 0; i < 8; i++) {
        const int pixA = pix0 + i * 64;
        const int pixB = pixA + 32;
        const float pA = pb[pixA];
        const float pB = pb[pixB];
        const float xrA = (float)(pixA >> 8) * nh;
        const float xcA = (float)(pixA & 255) * nw;
        const float xrB = (float)(pixB >> 8) * nh;
        const float xcB = (float)(pixB & 255) * nw;
        // (1-p)*MAXD + 1e-6  (the wd + 1e-6 epsilon folded in)
        const float bA = (1.0f - pA) * MAXD + 1e-6f;
        const float bB = (1.0f - pB) * MAXD + 1e-6f;
        const v2f xrA2 = {xrA, xrA}, xcA2 = {xcA, xcA};
        const v2f xrB2 = {xrB, xrB}, xcB2 = {xcB, xcB};
        const v2f pA2  = {pA, pA},   bA2  = {bA, bA};
        const v2f pB2  = {pB, pB},   bB2  = {bB, bB};
        float mA = 1e30f, mB = 1e30f;

#pragma unroll
        for (int j2 = 0; j2 < 8; j2++) {
            const v2f yx = *(const v2f*)&ysx[ysbase + 2 * j2];
            const v2f yy = *(const v2f*)&ysy[ysbase + 2 * j2];
            // pixel A — packed over the g-pair
            v2f dxA = xrA2 - yx, dyA = xcA2 - yy;
            v2f sA  = dxA * dxA + dyA * dyA;          // pk_mul + pk_fma
            float dAlo = __builtin_amdgcn_sqrtf(sA.x);
            float dAhi = __builtin_amdgcn_sqrtf(sA.y);
            mA = fminf(mA, fminf(dAlo, dAhi));        // v_min3
            v2f dA2 = {dAlo, dAhi};
            v2f tA  = pA2 * dA2 + bA2;                // wd + 1e-6
            v2f uA  = tA * tA; uA = uA * uA; uA = uA * uA; uA = uA * tA; // t^9
            v2f rcA = {__builtin_amdgcn_rcpf(uA.x), __builtin_amdgcn_rcpf(uA.y)};
            // pixel B
            v2f dxB = xrB2 - yx, dyB = xcB2 - yy;
            v2f sB  = dxB * dxB + dyB * dyB;
            float dBlo = __builtin_amdgcn_sqrtf(sB.x);
            float dBhi = __builtin_amdgcn_sqrtf(sB.y);
            mB = fminf(mB, fminf(dBlo, dBhi));
            v2f dB2 = {dBlo, dBhi};
            v2f tB  = pB2 * dB2 + bB2;
            v2f uB  = tB * tB; uB = uB * uB; uB = uB * uB; uB = uB * tB;
            v2f rcB = {__builtin_amdgcn_rcpf(uB.x), __builtin_amdgcn_rcpf(uB.y)};
            acc2[j2] += (rcA + rcB);
        }
        // min over all 128 g: combine the 8 chunk-lanes sharing this pixel
        mA = fminf(mA, __shfl_xor(mA, 1)); mA = fminf(mA, __shfl_xor(mA, 2));
        mA = fminf(mA, __shfl_xor(mA, 4));
        mB = fminf(mB, __shfl_xor(mB, 1)); mB = fminf(mB, __shfl_xor(mB, 2));
        mB = fminf(mB, __shfl_xor(mB, 4));
        t1acc = fmaf(pA, mA, t1acc);
        t1acc = fmaf(pB, mB, t1acc);
        pacc += pA + pB;
    }

    // unpack packed accumulators to per-g scalars (g = chunk*16 + 2*j2 + half)
    float acc[16];
#pragma unroll
    for (int j2 = 0; j2 < 8; j2++) {
        acc[2 * j2]     = acc2[j2].x;
        acc[2 * j2 + 1] = acc2[j2].y;
    }

    // per-g sums: reduce across the 8 same-chunk lanes of this wave
#pragma unroll
    for (int j = 0; j < 16; j++) {
        float v = acc[j];
        v += __shfl_xor(v, 8);  v += __shfl_xor(v, 16); v += __shfl_xor(v, 32);
        acc[j] = v;
    }
    t1acc = wave_sum(t1acc);   // each pixel counted 8x (once per chunk lane)
    pacc  = wave_sum(pacc);

    if (lane < 8) {
#pragma unroll
        for (int j = 0; j < 16; j++) redS[wv][lane * 17 + j] = acc[j];
    }
    if (lane == 0) redT[wv] = make_float2(t1acc, pacc);
    __syncthreads();

    // coalesced partials write: row `bid`, 128 consecutive floats + (t1,p)
    if (tid < GG) {
        const int idx = (tid >> 4) * 17 + (tid & 15);   // g == tid
        part[bid * ROWW + tid] =
            redS[0][idx] + redS[1][idx] + redS[2][idx] + redS[3][idx];
    } else if (tid == GG) {
        float t1 = redT[0].x + redT[1].x + redT[2].x + redT[3].x;
        float pp = redT[0].y + redT[1].y + redT[2].y + redT[3].y;
        part[bid * ROWW + 128] = t1 * 0.125f;   // undo 8x pixel multiplicity
        part[bid * ROWW + 129] = pp * 0.125f;
    }

    // ---- completion protocol: last block of batch b runs b's finalize ----
    __threadfence();          // every thread publishes its partials writes
    __syncthreads();
    if (tid == 0) {
        unsigned int old =
            atomicAdd((unsigned int*)(part + RES_OFF + 32) + b, 1u);
        doFin = (old == TGT_B) ? 1u : 0u;
    }
    __syncthreads();

    if (doFin) {              // block-uniform branch
        __threadfence();      // acquire side: other blocks' partials visible
        const int g    = tid & 127;
        const int half = tid >> 7;     // 0: rows 0..63, 1: rows 64..127

        const float* base2 = part + (b * BPB + half * 64) * ROWW + g;
        float s = 0.0f;
#pragma unroll 8
        for (int k = 0; k < 64; k++) s += base2[k * ROWW];

        if (half == 1) sh[g] = s;
        __syncthreads();

        float a2 = 0.0f;
        float2 tp = make_float2(0.0f, 0.0f);
        if (half == 0) {
            float tot  = s + sh[g];
            float mean = tot * (1.0f / (float)NPIX);
            a2 = powf(mean, -0.111111111111111111f);   // 1 / P_EXP
            tp = *(const float2*)(part + (b * BPB + g) * ROWW + 128);
        }

        float wa = wave_sum(a2);
        float wt = wave_sum(tp.x);
        float wp = wave_sum(tp.y);

        if (lane == 0) { rA[wv] = wa; rT[wv] = wt; rP[wv] = wp; }
        __syncthreads();

        if (tid == 0) {
            float t2b = rA[0] + rA[1] + rA[2] + rA[3];   // waves 2,3 are 0
            float t1b = rT[0] + rT[1] + rT[2] + rT[3];
            float ppb = rP[0] + rP[1] + rP[2] + rP[3];
            part[RES_OFF + 2 * b]     = t1b / (ppb + 1e-6f);
            part[RES_OFF + 2 * b + 1] = t2b;
            __threadfence();
            unsigned int old =
                atomicAdd((unsigned int*)(part + RES_OFF + 40), 1u);
            if (old == TGT_G) {
                __threadfence();
                float s1 = 0.0f, s2 = 0.0f;
#pragma unroll
                for (int q = 0; q < BB; q++) {
                    s1 += part[RES_OFF + 2 * q];
                    s2 += part[RES_OFF + 2 * q + 1];
                }
                out[0] = s1 * (1.0f / (float)BB) +
                         s2 * (1.0f / (float)(BB * GG));
            }
        }
    }
}

extern "C" void kernel_launch(void* const* d_in, const int* in_sizes, int n_in,
                              void* d_out, int out_size, void* d_ws, size_t ws_size,
                              hipStream_t stream) {
    const float* prob = (const float*)d_in[0];   // [B, H, W]
    const float* gt   = (const float*)d_in[1];   // [B, G, 2]
    const float* osz  = (const float*)d_in[2];   // [B, 2]
    float* out  = (float*)d_out;                 // [1]
    float* part = (float*)d_ws;                  // partials + results + counters

    whd_fused<<<BB * BPB, 256, 0, stream>>>(prob, gt, osz, part, out);
}

// Round 13
// 84.805 us; speedup vs baseline: 1.6980x; 1.6980x over previous
//
#include <hip/hip_runtime.h>
#include <math.h>

// Weighted Hausdorff Distance — B=8, H=W=256 (N=65536 pixels), G=128.
// TWO kernels: cross-block visibility via the kernel boundary (one implicit
// device-scope flush) — measured 80 µs cheaper than an in-kernel fence/atomic
// protocol on MI355X (round 11: per-XCD L2 writeback storm).
// Main kernel: 8-lane groups share a pixel-pair; each lane owns a 16-g chunk
// processed as 8 packed g-pairs (v2f -> v_pk_* f32 ops on gfx950).
// GT coords in SoA LDS (ysx/ysy), chunk stride 18 floats: conflict-free
// aligned ds_read_b64 per g-pair.
// Partials layout: part[row][132], row = b*128 + blk (1024 rows).
//   cols 0..127 : per-g block sums of (wd+1e-6)^-9
//   col  128    : block sum of p*min_d
//   col  129    : block sum of p
// Results area at float offset RES_OFF: 2 floats per b (a1_b, t2sum_b),
// completion counter (uint) at RES_OFF+16. Counter zeroed by whd_main
// block 0 each call (kernel-boundary ordering), finalize uses device-scope
// atomicAdd + threadfence for the last-block combine (8 blocks only — cheap).

#define HH 256
#define WW 256
#define BB 8
#define GG 128
#define NPIX (HH * WW)
#define BPB 128                       // blocks per batch item
#define ROWW 132                      // padded row width
#define RES_OFF (1024 * ROWW)
#define MAXD 362.03867196751236f      // sqrt(256^2 + 256^2)

typedef float v2f __attribute__((ext_vector_type(2)));

__device__ __forceinline__ float wave_sum(float v) {
    v += __shfl_xor(v, 1);  v += __shfl_xor(v, 2);  v += __shfl_xor(v, 4);
    v += __shfl_xor(v, 8);  v += __shfl_xor(v, 16); v += __shfl_xor(v, 32);
    return v;
}

__global__ __launch_bounds__(256, 4) void whd_main(const float* __restrict__ prob,
                                                   const float* __restrict__ gt,
                                                   const float* __restrict__ osz,
                                                   float* __restrict__ part) {
    const int bid  = blockIdx.x;
    const int b    = bid >> 7;            // / BPB
    const int blk  = bid & (BPB - 1);
    const int tid  = threadIdx.x;
    const int lane = tid & 63;
    const int wv   = tid >> 6;
    const int chunk = tid & 7;            // which 16-g chunk this lane owns
    const int pt    = tid >> 3;           // pixel-slot id, 0..31

    __shared__ float ysx[144];            // SoA, chunk c at offset c*18
    __shared__ float ysy[144];
    __shared__ float redS[4][137];
    __shared__ float2 redT[4];

    // re-zero the finalize completion counter every call (ws is 0xAA-poisoned)
    if (bid == 0 && tid == 129) {
        *(unsigned int*)(part + RES_OFF + 16) = 0u;
    }

    const float nh = osz[b * 2]     * (1.0f / (float)HH);
    const float nw = osz[b * 2 + 1] * (1.0f / (float)WW);

    if (tid < GG) {
        float gr = gt[(b * GG + tid) * 2];
        float gc = gt[(b * GG + tid) * 2 + 1];
        const int idx = (tid >> 4) * 18 + (tid & 15);
        ysx[idx] = gr * nh;
        ysy[idx] = gc * nw;
    }
    __syncthreads();

    const float* pb = prob + b * NPIX;

    v2f acc2[8];
#pragma unroll
    for (int j = 0; j < 8; j++) acc2[j] = (v2f)(0.0f);
    float t1acc = 0.0f, pacc = 0.0f;

    const int ysbase = chunk * 18;
    const int pix0   = blk * 512 + pt;

#pragma unroll 1
    for (int i = 0; i < 8; i++) {
        const int pixA = pix0 + i * 64;
        const int pixB = pixA + 32;
        const float pA = pb[pixA];
        const float pB = pb[pixB];
        const float xrA = (float)(pixA >> 8) * nh;
        const float xcA = (float)(pixA & 255) * nw;
        const float xrB = (float)(pixB >> 8) * nh;
        const float xcB = (float)(pixB & 255) * nw;
        // (1-p)*MAXD + 1e-6  (the wd + 1e-6 epsilon folded in)
        const float bA = (1.0f - pA) * MAXD + 1e-6f;
        const float bB = (1.0f - pB) * MAXD + 1e-6f;
        const v2f xrA2 = {xrA, xrA}, xcA2 = {xcA, xcA};
        const v2f xrB2 = {xrB, xrB}, xcB2 = {xcB, xcB};
        const v2f pA2  = {pA, pA},   bA2  = {bA, bA};
        const v2f pB2  = {pB, pB},   bB2  = {bB, bB};
        float mA = 1e30f, mB = 1e30f;

#pragma unroll
        for (int j2 = 0; j2 < 8; j2++) {
            const v2f yx = *(const v2f*)&ysx[ysbase + 2 * j2];
            const v2f yy = *(const v2f*)&ysy[ysbase + 2 * j2];
            // pixel A — packed over the g-pair
            v2f dxA = xrA2 - yx, dyA = xcA2 - yy;
            v2f sA  = dxA * dxA + dyA * dyA;          // pk_mul + pk_fma
            float dAlo = __builtin_amdgcn_sqrtf(sA.x);
            float dAhi = __builtin_amdgcn_sqrtf(sA.y);
            mA = fminf(mA, fminf(dAlo, dAhi));        // v_min3
            v2f dA2 = {dAlo, dAhi};
            v2f tA  = pA2 * dA2 + bA2;                // wd + 1e-6
            v2f uA  = tA * tA; uA = uA * uA; uA = uA * uA; uA = uA * tA; // t^9
            v2f rcA = {__builtin_amdgcn_rcpf(uA.x), __builtin_amdgcn_rcpf(uA.y)};
            // pixel B
            v2f dxB = xrB2 - yx, dyB = xcB2 - yy;
            v2f sB  = dxB * dxB + dyB * dyB;
            float dBlo = __builtin_amdgcn_sqrtf(sB.x);
            float dBhi = __builtin_amdgcn_sqrtf(sB.y);
            mB = fminf(mB, fminf(dBlo, dBhi));
            v2f dB2 = {dBlo, dBhi};
            v2f tB  = pB2 * dB2 + bB2;
            v2f uB  = tB * tB; uB = uB * uB; uB = uB * uB; uB = uB * tB;
            v2f rcB = {__builtin_amdgcn_rcpf(uB.x), __builtin_amdgcn_rcpf(uB.y)};
            acc2[j2] += (rcA + rcB);
        }
        // min over all 128 g: combine the 8 chunk-lanes sharing this pixel
        mA = fminf(mA, __shfl_xor(mA, 1)); mA = fminf(mA, __shfl_xor(mA, 2));
        mA = fminf(mA, __shfl_xor(mA, 4));
        mB = fminf(mB, __shfl_xor(mB, 1)); mB = fminf(mB, __shfl_xor(mB, 2));
        mB = fminf(mB, __shfl_xor(mB, 4));
        t1acc = fmaf(pA, mA, t1acc);
        t1acc = fmaf(pB, mB, t1acc);
        pacc += pA + pB;
    }

    // unpack packed accumulators to per-g scalars (g = chunk*16 + 2*j2 + half)
    float acc[16];
#pragma unroll
    for (int j2 = 0; j2 < 8; j2++) {
        acc[2 * j2]     = acc2[j2].x;
        acc[2 * j2 + 1] = acc2[j2].y;
    }

    // per-g sums: reduce across the 8 same-chunk lanes of this wave
#pragma unroll
    for (int j = 0; j < 16; j++) {
        float v = acc[j];
        v += __shfl_xor(v, 8);  v += __shfl_xor(v, 16); v += __shfl_xor(v, 32);
        acc[j] = v;
    }
    t1acc = wave_sum(t1acc);   // each pixel counted 8x (once per chunk lane)
    pacc  = wave_sum(pacc);

    if (lane < 8) {
#pragma unroll
        for (int j = 0; j < 16; j++) redS[wv][lane * 17 + j] = acc[j];
    }
    if (lane == 0) redT[wv] = make_float2(t1acc, pacc);
    __syncthreads();

    // coalesced partials write: row `bid`, 128 consecutive floats + (t1,p)
    if (tid < GG) {
        const int idx = (tid >> 4) * 17 + (tid & 15);   // g == tid
        part[bid * ROWW + tid] =
            redS[0][idx] + redS[1][idx] + redS[2][idx] + redS[3][idx];
    } else if (tid == GG) {
        float t1 = redT[0].x + redT[1].x + redT[2].x + redT[3].x;
        float pp = redT[0].y + redT[1].y + redT[2].y + redT[3].y;
        part[bid * ROWW + 128] = t1 * 0.125f;   // undo 8x pixel multiplicity
        part[bid * ROWW + 129] = pp * 0.125f;
    }
}

__global__ __launch_bounds__(256) void whd_final(float* __restrict__ part,
                                                 float* __restrict__ out) {
    const int bb   = blockIdx.x;        // 0..7, one block per batch item
    const int tid  = threadIdx.x;
    const int g    = tid & 127;
    const int half = tid >> 7;          // 0: rows 0..63, 1: rows 64..127

    // term2 partial: sum this b's rows (split in 2 halves); coalesced over g
    const float* base = part + (bb * BPB + half * 64) * ROWW + g;
    float s = 0.0f;
#pragma unroll 8
    for (int k = 0; k < 64; k++) s += base[k * ROWW];

    __shared__ float sh[128];
    if (half == 1) sh[g] = s;
    __syncthreads();

    float a2 = 0.0f;
    float2 tp = make_float2(0.0f, 0.0f);
    if (half == 0) {
        float tot  = s + sh[g];
        float mean = tot * (1.0f / (float)NPIX);
        a2 = powf(mean, -0.111111111111111111f);   // 1 / P_EXP
        // term1 partials: thread g reads row (bb*BPB+g)'s (t1, p)
        tp = *(const float2*)(part + (bb * BPB + g) * ROWW + 128);
    }

    float wa = wave_sum(a2);
    float wt = wave_sum(tp.x);
    float wp = wave_sum(tp.y);

    __shared__ float rA[4], rT[4], rP[4];
    if ((tid & 63) == 0) { rA[tid >> 6] = wa; rT[tid >> 6] = wt; rP[tid >> 6] = wp; }
    __syncthreads();

    if (tid == 0) {
        float t2b = rA[0] + rA[1] + rA[2] + rA[3];   // waves 2,3 contribute 0
        float t1b = rT[0] + rT[1] + rT[2] + rT[3];
        float ppb = rP[0] + rP[1] + rP[2] + rP[3];
        part[RES_OFF + 2 * bb]     = t1b / (ppb + 1e-6f);
        part[RES_OFF + 2 * bb + 1] = t2b;
        __threadfence();
        unsigned int old = atomicAdd((unsigned int*)(part + RES_OFF + 16), 1u);
        if (old == BB - 1) {
            __threadfence();
            float s1 = 0.0f, s2 = 0.0f;
#pragma unroll
            for (int q = 0; q < BB; q++) {
                s1 += part[RES_OFF + 2 * q];
                s2 += part[RES_OFF + 2 * q + 1];
            }
            out[0] = s1 * (1.0f / (float)BB) + s2 * (1.0f / (float)(BB * GG));
        }
    }
}

extern "C" void kernel_launch(void* const* d_in, const int* in_sizes, int n_in,
                              void* d_out, int out_size, void* d_ws, size_t ws_size,
                              hipStream_t stream) {
    const float* prob = (const float*)d_in[0];   // [B, H, W]
    const float* gt   = (const float*)d_in[1];   // [B, G, 2]
    const float* osz  = (const float*)d_in[2];   // [B, 2]
    float* out  = (float*)d_out;                 // [1]
    float* part = (float*)d_ws;                  // partials + results + counter

    whd_main<<<BB * BPB, 256, 0, stream>>>(prob, gt, osz, part);
    whd_final<<<BB, 256, 0, stream>>>(part, out);
}